// Round 4
// baseline (1046.222 us; speedup 1.0000x reference)
//
#include <hip/hip_runtime.h>
#include <hip/hip_fp16.h>

#define B_    64
#define V1_   4096
#define V2_   1024
#define DF_   8
#define K_    25
#define KP_   32
#define F1_   32
#define F2_   64
#define FC1F_ 512
#define FC2F_ 10
#define E1_   65536
#define E2_   16384
#define C1_   512
#define C2_   2048
#define FCIN_ 16384

typedef short bf16x8 __attribute__((ext_vector_type(8)));
typedef float f32x4  __attribute__((ext_vector_type(4)));

__device__ __forceinline__ unsigned short f2bf(float x) {
    unsigned u = __float_as_uint(x);
    u += 0x7FFFu + ((u >> 16) & 1u);
    return (unsigned short)(u >> 16);
}

// ---------- input transpose: x[b,v,fin] -> X0T[(fin*64+b)][v] ----------
__global__ __launch_bounds__(256) void k_transpose_x(const float* __restrict__ x,
                                                     float* __restrict__ X0T) {
    __shared__ float tsh[DF_][B_][16];
    const int t = threadIdx.x;
    const int v0 = blockIdx.x * 16;
    for (int rep = 0; rep < 4; ++rep) {
        int idx = rep*256 + t;
        int b = idx >> 4, vv = idx & 15;
        const float4* p = (const float4*)&x[((size_t)b*V1_ + v0 + vv)*DF_];
        float4 a0 = p[0], a1 = p[1];
        tsh[0][b][vv]=a0.x; tsh[1][b][vv]=a0.y; tsh[2][b][vv]=a0.z; tsh[3][b][vv]=a0.w;
        tsh[4][b][vv]=a1.x; tsh[5][b][vv]=a1.y; tsh[6][b][vv]=a1.z; tsh[7][b][vv]=a1.w;
    }
    __syncthreads();
    for (int rep = 0; rep < 32; ++rep) {
        int idx = rep*256 + t;
        int vv = idx & 15, b = (idx >> 4) & 63, fin = idx >> 10;
        X0T[(size_t)(fin*64 + b)*V1_ + v0 + vv] = tsh[fin][b][vv];
    }
}

// ---------- CSR build: histogram -> windowed degree-sort -> scan -> scatter ----------
__global__ __launch_bounds__(256) void k_count(const int* __restrict__ rows, int E,
                                               int* __restrict__ cnt) {
    int e = blockIdx.x*256 + threadIdx.x;
    if (e < E) atomicAdd(&cnt[rows[e]], 1);
}

// per 256-row window: sorted slot assignment (rank by degree)
__global__ __launch_bounds__(256) void k_rank(const int* __restrict__ cnt,
                                              int* __restrict__ orig,
                                              int* __restrict__ sortslot,
                                              int* __restrict__ pdeg) {
    __shared__ int degs[256];
    const int w0 = blockIdx.x*256;
    const int t = threadIdx.x;
    const int d = cnt[w0 + t];
    degs[t] = d;
    __syncthreads();
    int rank = 0;
    for (int i = 0; i < 256; ++i) {
        int di = degs[i];
        rank += (di < d || (di == d && i < t)) ? 1 : 0;
    }
    orig[w0 + rank] = w0 + t;
    sortslot[w0 + t] = w0 + rank;
    pdeg[w0 + rank] = (d + 3) & ~3;
}

__global__ __launch_bounds__(256) void k_scan(const int* __restrict__ pdeg, int V,
                                              int* __restrict__ offs, int* __restrict__ cursor) {
    __shared__ int psum[256];
    int t = threadIdx.x;
    int chunk = V >> 8;
    int lo = t*chunk;
    int s = 0;
    for (int i = lo; i < lo+chunk; ++i) s += pdeg[i];
    psum[t] = s;
    __syncthreads();
    for (int off = 1; off < 256; off <<= 1) {
        int val = (t >= off) ? psum[t-off] : 0;
        __syncthreads();
        psum[t] += val;
        __syncthreads();
    }
    int run = (t == 0) ? 0 : psum[t-1];
    for (int i = lo; i < lo+chunk; ++i) {
        offs[i] = run; cursor[i] = run;
        run += pdeg[i];
    }
    if (t == 255) offs[V] = run;
}

// edge payload: {col*8 (LDS byte offset), f32 weight bits}
__global__ __launch_bounds__(256) void k_scatter(const int* __restrict__ rows,
                                                 const int* __restrict__ cols,
                                                 const float* __restrict__ vals, int E,
                                                 const int* __restrict__ sortslot,
                                                 int* __restrict__ cursor,
                                                 uint2* __restrict__ ep) {
    int e = blockIdx.x*256 + threadIdx.x;
    if (e < E) {
        int p = atomicAdd(&cursor[sortslot[rows[e]]], 1);
        ep[p] = make_uint2((unsigned)cols[e]*8u, __float_as_uint(vals[e]));
    }
}

// ---------- persistent Chebyshev recursion (2 columns/block, LDS ping-pong) ----------
// stack layout: [c][w(0..3)][v][kk(0..7)] bf16 (v = ORIGINAL vertex id)
template<int V, int THREADS>
__global__ __launch_bounds__(THREADS) void k_cheb(
        const float* __restrict__ X0T,
        const int* __restrict__ offs, const int* __restrict__ orig,
        const uint2* __restrict__ ep,
        unsigned short* __restrict__ stack) {
    constexpr int RPT = V / THREADS;
    __shared__ float bufA[V*2];
    __shared__ float bufB[V*2];
    const int c0 = blockIdx.x * 2;
    const int t = threadIdx.x;
    int e0r[RPT], e1r[RPT], ovr[RPT];
    unsigned pk[RPT][2][4];
    unsigned tlo[RPT][2];

#pragma unroll
    for (int r = 0; r < RPT; ++r) {
        int s = r*THREADS + t;
        e0r[r] = offs[s]; e1r[r] = offs[s+1];
        int ov = orig[s];
        ovr[r] = ov;
        float x0 = X0T[(size_t)c0*V + ov];
        float x1 = X0T[(size_t)(c0+1)*V + ov];
        bufA[ov*2]   = x0; tlo[r][0] = f2bf(x0);
        bufA[ov*2+1] = x1; tlo[r][1] = f2bf(x1);
    }
    __syncthreads();

    for (int w = 0; w < 4; ++w) {
#pragma unroll
        for (int kk = 0; kk < 8; ++kk) {
            if (w == 0 && kk == 0) continue;           // k=0 handled at init
            if (w == 3 && kk >= 1) {                   // zero-pad k=25..31
#pragma unroll
                for (int r = 0; r < RPT; ++r)
#pragma unroll
                    for (int j = 0; j < 2; ++j) {
                        if (kk & 1) pk[r][j][kk>>1] = tlo[r][j];
                        else        tlo[r][j] = 0;
                    }
                continue;
            }
            const float* __restrict__ src = (kk & 1) ? bufA : bufB;
            float* __restrict__ dst       = (kk & 1) ? bufB : bufA;
#pragma unroll
            for (int r = 0; r < RPT; ++r) {
                float a00=0,a01=0,a10=0,a11=0,a20=0,a21=0,a30=0,a31=0;
                const int e1 = e1r[r];
                for (int e = e0r[r]; e < e1; e += 4) {
                    const uint4 q0 = *(const uint4*)&ep[e];
                    const uint4 q1 = *(const uint4*)&ep[e+2];
                    const float2 g0 = *(const float2*)((const char*)src + q0.x);
                    const float2 g1 = *(const float2*)((const char*)src + q0.z);
                    const float2 g2 = *(const float2*)((const char*)src + q1.x);
                    const float2 g3 = *(const float2*)((const char*)src + q1.z);
                    const float w0 = __uint_as_float(q0.y), w1 = __uint_as_float(q0.w);
                    const float w2 = __uint_as_float(q1.y), w3 = __uint_as_float(q1.w);
                    a00 = fmaf(w0, g0.x, a00); a01 = fmaf(w0, g0.y, a01);
                    a10 = fmaf(w1, g1.x, a10); a11 = fmaf(w1, g1.y, a11);
                    a20 = fmaf(w2, g2.x, a20); a21 = fmaf(w2, g2.y, a21);
                    a30 = fmaf(w3, g3.x, a30); a31 = fmaf(w3, g3.y, a31);
                }
                float s0 = (a00+a10)+(a20+a30);
                float s1 = (a01+a11)+(a21+a31);
                const int ov = ovr[r];
                float x0n, x1n;
                if (w == 0 && kk == 1) { x0n = s0; x1n = s1; }
                else { x0n = 2.f*s0 - dst[ov*2]; x1n = 2.f*s1 - dst[ov*2+1]; }
                dst[ov*2]   = x0n;
                dst[ov*2+1] = x1n;
                unsigned h0 = f2bf(x0n), h1 = f2bf(x1n);
                if (kk & 1) { pk[r][0][kk>>1] = tlo[r][0] | (h0 << 16);
                              pk[r][1][kk>>1] = tlo[r][1] | (h1 << 16); }
                else        { tlo[r][0] = h0; tlo[r][1] = h1; }
            }
            __syncthreads();
        }
#pragma unroll
        for (int r = 0; r < RPT; ++r)
#pragma unroll
            for (int j = 0; j < 2; ++j)
                *(uint4*)&stack[((size_t)(c0+j)*KP_ + w*8)*V + (size_t)ovr[r]*8] =
                    make_uint4(pk[r][j][0], pk[r][j][1], pk[r][j][2], pk[r][j][3]);
    }
}

// ---------- W prep: Wb[fin][g][f][kk] = bf16(W[f][fin*25 + g*8+kk]), 0-padded ----------
template<int FIN, int F>
__global__ __launch_bounds__(256) void k_wprep(const float* __restrict__ W,
                                               unsigned short* __restrict__ Wb) {
    int idx = blockIdx.x*256 + threadIdx.x;
    int kk  = idx & 7;
    int f   = (idx >> 3) % F;
    int g   = (idx >> 3) / F % 4;
    int fin = idx / (8*F*4);
    int k = g*8 + kk;
    Wb[idx] = (k < K_) ? f2bf(W[(size_t)f*(FIN*K_) + fin*K_ + k]) : 0;
}

// ---------- layer-1 MFMA GEMM + relu + pool -> X0T2[(f*64+b)][v2] ----------
__global__ __launch_bounds__(256) void k_gemm1(const unsigned short* __restrict__ stack,
                                               const unsigned short* __restrict__ Wb,
                                               const float* __restrict__ bias,
                                               float* __restrict__ X0T2) {
    __shared__ float Tsm[32][36];
    const int t = threadIdx.x, lane = t & 63, wave = t >> 6;
    const int b = blockIdx.x;
    const int v0 = blockIdx.y*128 + wave*32;
    const int m = lane & 15, g = lane >> 4;

    f32x4 acc[2][2];
#pragma unroll
    for (int mt = 0; mt < 2; ++mt)
#pragma unroll
        for (int ft = 0; ft < 2; ++ft) acc[mt][ft] = (f32x4){0.f,0.f,0.f,0.f};

#pragma unroll
    for (int fin = 0; fin < DF_; ++fin) {
        const size_t abase = ((size_t)((fin*64+b)*KP_ + g*8))*V1_ + (size_t)(v0+m)*8;
        const bf16x8 a0 = *(const bf16x8*)&stack[abase];
        const bf16x8 a1 = *(const bf16x8*)&stack[abase + 16*8];
        const bf16x8 w0 = *(const bf16x8*)&Wb[((fin*4+g)*F1_ + m)*8];
        const bf16x8 w1 = *(const bf16x8*)&Wb[((fin*4+g)*F1_ + 16 + m)*8];
        acc[0][0] = __builtin_amdgcn_mfma_f32_16x16x32_bf16(a0, w0, acc[0][0], 0,0,0);
        acc[0][1] = __builtin_amdgcn_mfma_f32_16x16x32_bf16(a0, w1, acc[0][1], 0,0,0);
        acc[1][0] = __builtin_amdgcn_mfma_f32_16x16x32_bf16(a1, w0, acc[1][0], 0,0,0);
        acc[1][1] = __builtin_amdgcn_mfma_f32_16x16x32_bf16(a1, w1, acc[1][1], 0,0,0);
    }
    float bv[2] = { bias[m], bias[16+m] };
#pragma unroll
    for (int mt = 0; mt < 2; ++mt)
#pragma unroll
        for (int ft = 0; ft < 2; ++ft) {
            f32x4 a = acc[mt][ft];
            float mx = fmaxf(fmaxf(a[0],a[1]), fmaxf(a[2],a[3])) + bv[ft];
            Tsm[ft*16 + m][wave*8 + mt*4 + g] = fmaxf(mx, 0.f);
        }
    __syncthreads();
    const int f = t >> 3, vg = t & 7;
    float4 o = *(const float4*)&Tsm[f][vg*4];
    *(float4*)&X0T2[(size_t)(f*64+b)*V2_ + blockIdx.y*32 + vg*4] = o;
}

// ---------- layer-2 MFMA GEMM + relu + pool -> FCINT[v2*64+f][b] ----------
__global__ __launch_bounds__(256) void k_gemm2(const unsigned short* __restrict__ stack,
                                               const unsigned short* __restrict__ Wb,
                                               const float* __restrict__ bias,
                                               float* __restrict__ FCINT) {
    const int t = threadIdx.x, lane = t & 63, wave = t >> 6;
    const int b = blockIdx.x;
    const int v0 = blockIdx.y*128 + wave*32;
    const int m = lane & 15, g = lane >> 4;

    f32x4 acc[2][4];
#pragma unroll
    for (int mt = 0; mt < 2; ++mt)
#pragma unroll
        for (int ft = 0; ft < 4; ++ft) acc[mt][ft] = (f32x4){0.f,0.f,0.f,0.f};

#pragma unroll 4
    for (int fin = 0; fin < F1_; ++fin) {
        const size_t abase = ((size_t)((fin*64+b)*KP_ + g*8))*V2_ + (size_t)(v0+m)*8;
        const bf16x8 a0 = *(const bf16x8*)&stack[abase];
        const bf16x8 a1 = *(const bf16x8*)&stack[abase + 16*8];
#pragma unroll
        for (int ft = 0; ft < 4; ++ft) {
            const bf16x8 bw = *(const bf16x8*)&Wb[((fin*4+g)*F2_ + ft*16 + m)*8];
            acc[0][ft] = __builtin_amdgcn_mfma_f32_16x16x32_bf16(a0, bw, acc[0][ft], 0,0,0);
            acc[1][ft] = __builtin_amdgcn_mfma_f32_16x16x32_bf16(a1, bw, acc[1][ft], 0,0,0);
        }
    }
#pragma unroll
    for (int mt = 0; mt < 2; ++mt)
#pragma unroll
        for (int ft = 0; ft < 4; ++ft) {
            f32x4 a = acc[mt][ft];
            float mx = fmaxf(fmaxf(a[0],a[1]), fmaxf(a[2],a[3])) + bias[ft*16 + m];
            mx = fmaxf(mx, 0.f);
            int v2 = blockIdx.y*32 + wave*8 + mt*4 + g;
            FCINT[((size_t)v2*64 + ft*16 + m)*64 + b] = mx;
        }
}

// ---------- FC1: O[b][j] (+= atomics over i-splits), AT layout [i][b] ----------
__global__ __launch_bounds__(256) void k_fc1_init(const float* __restrict__ bias,
                                                  float* __restrict__ O) {
    int idx = blockIdx.x*256 + threadIdx.x;
    O[idx] = bias[idx & (FC1F_-1)];
}

__global__ __launch_bounds__(256) void k_fc1(const float* __restrict__ AT,
                                             const float* __restrict__ W,
                                             float* __restrict__ O) {
    const int t = threadIdx.x;
    const int b = t & 63;
    const int jq = __builtin_amdgcn_readfirstlane(t >> 6);
    const int j0 = blockIdx.x*32 + jq*8;
    const int i0 = blockIdx.y*1024;
    float acc[8] = {};
    for (int i = i0; i < i0 + 1024; i += 4) {
        float a0 = AT[(size_t)(i+0)*64 + b];
        float a1 = AT[(size_t)(i+1)*64 + b];
        float a2 = AT[(size_t)(i+2)*64 + b];
        float a3 = AT[(size_t)(i+3)*64 + b];
#pragma unroll
        for (int jj = 0; jj < 8; ++jj) {
            const float* wp = &W[(size_t)(j0+jj)*FCIN_ + i];
            acc[jj] = fmaf(a0, wp[0], acc[jj]);
            acc[jj] = fmaf(a1, wp[1], acc[jj]);
            acc[jj] = fmaf(a2, wp[2], acc[jj]);
            acc[jj] = fmaf(a3, wp[3], acc[jj]);
        }
    }
#pragma unroll
    for (int jj = 0; jj < 8; ++jj)
        atomicAdd(&O[b*FC1F_ + j0 + jj], acc[jj]);
}

// ---------- FC2 (relu on FC1 output applied here) ----------
__global__ void k_fc2(const float* __restrict__ O1, const float* __restrict__ W2,
                      const float* __restrict__ b2, float* __restrict__ out) {
    int c = blockIdx.x;
    int b = threadIdx.x;
    float s = b2[c];
    for (int j = 0; j < FC1F_; ++j)
        s = fmaf(fmaxf(O1[b*FC1F_ + j], 0.f), W2[c*FC1F_ + j], s);
    out[b*FC2F_ + c] = s;
}

extern "C" void kernel_launch(void* const* d_in, const int* in_sizes, int n_in,
                              void* d_out, int out_size, void* d_ws, size_t ws_size,
                              hipStream_t stream) {
    const float* x   = (const float*)d_in[0];
    const int*   l1r = (const int*)d_in[1];
    const int*   l1c = (const int*)d_in[2];
    const float* l1v = (const float*)d_in[3];
    const int*   l2r = (const int*)d_in[4];
    const int*   l2c = (const int*)d_in[5];
    const float* l2v = (const float*)d_in[6];
    const float* w1  = (const float*)d_in[7];
    const float* b1  = (const float*)d_in[8];
    const float* w2  = (const float*)d_in[9];
    const float* b2  = (const float*)d_in[10];
    const float* fw1 = (const float*)d_in[11];
    const float* fb1 = (const float*)d_in[12];
    const float* fw2 = (const float*)d_in[13];
    const float* fb2 = (const float*)d_in[14];
    float* out = (float*)d_out;

    char* wsp = (char*)d_ws;
    size_t off = 0;
    auto alloc = [&](size_t bytes) -> void* {
        void* p = wsp + off;
        off += (bytes + 255) & ~size_t(255);
        return p;
    };
    float*          X0T1  = (float*)alloc((size_t)C1_*V1_*4);
    unsigned short* STACK = (unsigned short*)alloc((size_t)C1_*V1_*KP_*2);  // reused by layer 2
    float*          X0T2  = (float*)alloc((size_t)C2_*V2_*4);
    float*          FCINT = (float*)alloc((size_t)FCIN_*B_*4);
    float*          FC1O  = (float*)alloc((size_t)B_*FC1F_*4);
    unsigned short* WB1   = (unsigned short*)alloc((size_t)DF_*4*F1_*8*2);
    unsigned short* WB2   = (unsigned short*)alloc((size_t)F1_*4*F2_*8*2);
    int*   cnt1  = (int*)alloc(V1_*4);
    int*   offs1 = (int*)alloc((V1_+1)*4);
    int*   cur1  = (int*)alloc(V1_*4);
    int*   org1  = (int*)alloc(V1_*4);
    int*   slt1  = (int*)alloc(V1_*4);
    int*   pdg1  = (int*)alloc(V1_*4);
    uint2* ep1   = (uint2*)alloc((size_t)(E1_ + 4*V1_)*8);
    int*   cnt2  = (int*)alloc(V2_*4);
    int*   offs2 = (int*)alloc((V2_+1)*4);
    int*   cur2  = (int*)alloc(V2_*4);
    int*   org2  = (int*)alloc(V2_*4);
    int*   slt2  = (int*)alloc(V2_*4);
    int*   pdg2  = (int*)alloc(V2_*4);
    uint2* ep2   = (uint2*)alloc((size_t)(E2_ + 4*V2_)*8);

    // --- CSR build (degree-sorted within 256-row windows) + W prep ---
    hipMemsetAsync(cnt1, 0, V1_*4, stream);
    hipMemsetAsync(ep1, 0, (size_t)(E1_ + 4*V1_)*8, stream);
    hipMemsetAsync(cnt2, 0, V2_*4, stream);
    hipMemsetAsync(ep2, 0, (size_t)(E2_ + 4*V2_)*8, stream);
    hipLaunchKernelGGL(k_count,   dim3(E1_/256), dim3(256), 0, stream, l1r, E1_, cnt1);
    hipLaunchKernelGGL(k_rank,    dim3(V1_/256), dim3(256), 0, stream, cnt1, org1, slt1, pdg1);
    hipLaunchKernelGGL(k_scan,    dim3(1),       dim3(256), 0, stream, pdg1, V1_, offs1, cur1);
    hipLaunchKernelGGL(k_scatter, dim3(E1_/256), dim3(256), 0, stream, l1r, l1c, l1v, E1_, slt1, cur1, ep1);
    hipLaunchKernelGGL(k_count,   dim3(E2_/256), dim3(256), 0, stream, l2r, E2_, cnt2);
    hipLaunchKernelGGL(k_rank,    dim3(V2_/256), dim3(256), 0, stream, cnt2, org2, slt2, pdg2);
    hipLaunchKernelGGL(k_scan,    dim3(1),       dim3(256), 0, stream, pdg2, V2_, offs2, cur2);
    hipLaunchKernelGGL(k_scatter, dim3(E2_/256), dim3(256), 0, stream, l2r, l2c, l2v, E2_, slt2, cur2, ep2);
    hipLaunchKernelGGL((k_wprep<DF_,F1_>),  dim3(DF_*4*F1_*8/256),  dim3(256), 0, stream, w1, WB1);
    hipLaunchKernelGGL((k_wprep<F1_,F2_>),  dim3(F1_*4*F2_*8/256),  dim3(256), 0, stream, w2, WB2);

    // --- layer 1 ---
    hipLaunchKernelGGL(k_transpose_x, dim3(V1_/16), dim3(256), 0, stream, x, X0T1);
    hipLaunchKernelGGL((k_cheb<V1_,1024>), dim3(C1_/2), dim3(1024), 0, stream,
                       X0T1, offs1, org1, ep1, STACK);
    hipLaunchKernelGGL(k_gemm1, dim3(64, 32), dim3(256), 0, stream, STACK, WB1, b1, X0T2);

    // --- layer 2 ---
    hipLaunchKernelGGL((k_cheb<V2_,256>), dim3(C2_/2), dim3(256), 0, stream,
                       X0T2, offs2, org2, ep2, STACK);
    hipLaunchKernelGGL(k_gemm2, dim3(64, 8), dim3(256), 0, stream, STACK, WB2, b2, FCINT);

    // --- FC ---
    hipLaunchKernelGGL(k_fc1_init, dim3(B_*FC1F_/256), dim3(256), 0, stream, fb1, FC1O);
    hipLaunchKernelGGL(k_fc1, dim3(16, 16), dim3(256), 0, stream, FCINT, fw1, FC1O);
    hipLaunchKernelGGL(k_fc2, dim3(FC2F_), dim3(B_), 0, stream, FC1O, fw2, fb2, out);
}

// Round 5
// 730.249 us; speedup vs baseline: 1.4327x; 1.4327x over previous
//
#include <hip/hip_runtime.h>
#include <hip/hip_fp16.h>

#define B_    64
#define V1_   4096
#define V2_   1024
#define DF_   8
#define K_    25
#define NP_   13      /* u32 pair-planes per column: pairs (k0,k1)..(k24,-) */
#define F1_   32
#define F2_   64
#define FC1F_ 512
#define FC2F_ 10
#define E1_   65536
#define E2_   16384
#define C1_   512
#define C2_   2048
#define FCIN_ 16384

typedef short bf16x8 __attribute__((ext_vector_type(8)));
typedef float f32x4  __attribute__((ext_vector_type(4)));

__device__ __forceinline__ unsigned short f2bf(float x) {
    unsigned u = __float_as_uint(x);
    u += 0x7FFFu + ((u >> 16) & 1u);
    return (unsigned short)(u >> 16);
}

// ---------- input transpose: x[b,v,fin] -> X0T[(fin*64+b)][v] ----------
__global__ __launch_bounds__(256) void k_transpose_x(const float* __restrict__ x,
                                                     float* __restrict__ X0T) {
    __shared__ float tsh[DF_][B_][16];
    const int t = threadIdx.x;
    const int v0 = blockIdx.x * 16;
    for (int rep = 0; rep < 4; ++rep) {
        int idx = rep*256 + t;
        int b = idx >> 4, vv = idx & 15;
        const float4* p = (const float4*)&x[((size_t)b*V1_ + v0 + vv)*DF_];
        float4 a0 = p[0], a1 = p[1];
        tsh[0][b][vv]=a0.x; tsh[1][b][vv]=a0.y; tsh[2][b][vv]=a0.z; tsh[3][b][vv]=a0.w;
        tsh[4][b][vv]=a1.x; tsh[5][b][vv]=a1.y; tsh[6][b][vv]=a1.z; tsh[7][b][vv]=a1.w;
    }
    __syncthreads();
    for (int rep = 0; rep < 32; ++rep) {
        int idx = rep*256 + t;
        int vv = idx & 15, b = (idx >> 4) & 63, fin = idx >> 10;
        X0T[(size_t)(fin*64 + b)*V1_ + v0 + vv] = tsh[fin][b][vv];
    }
}

// ---------- CSR build (padded to 4-edge alignment, packed 4B edges) ----------
__global__ __launch_bounds__(256) void k_count(const int* __restrict__ rows, int E,
                                               int* __restrict__ cnt) {
    int e = blockIdx.x*256 + threadIdx.x;
    if (e < E) atomicAdd(&cnt[rows[e]], 1);
}

__global__ __launch_bounds__(256) void k_scan(const int* __restrict__ cnt, int V,
                                              int* __restrict__ offs, int* __restrict__ cursor) {
    __shared__ int psum[256];
    int t = threadIdx.x;
    int chunk = V >> 8;
    int lo = t*chunk;
    int s = 0;
    for (int i = lo; i < lo+chunk; ++i) s += (cnt[i] + 3) & ~3;
    psum[t] = s;
    __syncthreads();
    for (int off = 1; off < 256; off <<= 1) {
        int val = (t >= off) ? psum[t-off] : 0;
        __syncthreads();
        psum[t] += val;
        __syncthreads();
    }
    int run = (t == 0) ? 0 : psum[t-1];
    for (int i = lo; i < lo+chunk; ++i) {
        offs[i] = run; cursor[i] = run;
        run += (cnt[i] + 3) & ~3;
    }
    if (t == 255) offs[V] = run;
}

// edge payload: {f16 weight hi16, (col*4) lo16} -> col*4 = byte offset into f16x2 state
__global__ __launch_bounds__(256) void k_scatter(const int* __restrict__ rows,
                                                 const int* __restrict__ cols,
                                                 const float* __restrict__ vals, int E,
                                                 int* __restrict__ cursor,
                                                 unsigned* __restrict__ ep) {
    int e = blockIdx.x*256 + threadIdx.x;
    if (e < E) {
        int p = atomicAdd(&cursor[rows[e]], 1);
        unsigned hv = (unsigned)__half_as_ushort(__float2half(vals[e]));
        ep[p] = (hv << 16) | ((unsigned)cols[e] << 2);
    }
}

// ---------- persistent Chebyshev recursion: 2 cols/block, f16x2 LDS ping-pong ----------
// stack: u32 pair-planes  stk[(c*13 + pair)*V + v] = bf16(x_{2p}) | bf16(x_{2p+1})<<16
template<int V, int THREADS, int MINW>
__global__ __launch_bounds__(THREADS, MINW) void k_cheb(
        const float* __restrict__ X0T,
        const int* __restrict__ offs,
        const unsigned* __restrict__ ep,
        unsigned* __restrict__ stk) {
    constexpr int RPT = V / THREADS;
    __shared__ unsigned buf[2*V];
    const int c0 = blockIdx.x*2;
    const int t = threadIdx.x;
    int e0r[RPT], e1r[RPT];
    unsigned tlo0[RPT], tlo1[RPT];
    unsigned* __restrict__ p0 = stk + (size_t)(c0+0)*NP_*V;
    unsigned* __restrict__ p1 = stk + (size_t)(c0+1)*NP_*V;

    // k = 0
#pragma unroll
    for (int r = 0; r < RPT; ++r) {
        const int v = r*THREADS + t;
        e0r[r] = offs[v]; e1r[r] = offs[v+1];
        const float x0 = X0T[(size_t)c0*V + v];
        const float x1 = X0T[(size_t)(c0+1)*V + v];
        __half2 hh = __floats2half2_rn(x0, x1);
        buf[v] = *(const unsigned*)&hh;
        tlo0[r] = f2bf(x0); tlo1[r] = f2bf(x1);
    }
    __syncthreads();

    // one Chebyshev step: gather src, write dst; plane>=0 -> flush pair, else stash tlo
    auto step = [&](const unsigned* __restrict__ src, unsigned* __restrict__ dst,
                    bool first, bool last, int plane) {
#pragma unroll
        for (int r = 0; r < RPT; ++r) {
            const int v = r*THREADS + t;
            float s0a=0.f,s0b=0.f,s0c=0.f,s0d=0.f;
            float s1a=0.f,s1b=0.f,s1c=0.f,s1d=0.f;
            const int e1 = e1r[r];
            for (int e = e0r[r]; e < e1; e += 4) {
                const uint4 q = *(const uint4*)&ep[e];
                {
                    const float wf = __half2float(__ushort_as_half((unsigned short)(q.x>>16)));
                    const unsigned g = *(const unsigned*)((const char*)src + (q.x & 0xFFFFu));
                    s0a = fmaf(wf, __half2float(__ushort_as_half((unsigned short)(g & 0xFFFFu))), s0a);
                    s1a = fmaf(wf, __half2float(__ushort_as_half((unsigned short)(g >> 16))), s1a);
                }
                {
                    const float wf = __half2float(__ushort_as_half((unsigned short)(q.y>>16)));
                    const unsigned g = *(const unsigned*)((const char*)src + (q.y & 0xFFFFu));
                    s0b = fmaf(wf, __half2float(__ushort_as_half((unsigned short)(g & 0xFFFFu))), s0b);
                    s1b = fmaf(wf, __half2float(__ushort_as_half((unsigned short)(g >> 16))), s1b);
                }
                {
                    const float wf = __half2float(__ushort_as_half((unsigned short)(q.z>>16)));
                    const unsigned g = *(const unsigned*)((const char*)src + (q.z & 0xFFFFu));
                    s0c = fmaf(wf, __half2float(__ushort_as_half((unsigned short)(g & 0xFFFFu))), s0c);
                    s1c = fmaf(wf, __half2float(__ushort_as_half((unsigned short)(g >> 16))), s1c);
                }
                {
                    const float wf = __half2float(__ushort_as_half((unsigned short)(q.w>>16)));
                    const unsigned g = *(const unsigned*)((const char*)src + (q.w & 0xFFFFu));
                    s0d = fmaf(wf, __half2float(__ushort_as_half((unsigned short)(g & 0xFFFFu))), s0d);
                    s1d = fmaf(wf, __half2float(__ushort_as_half((unsigned short)(g >> 16))), s1d);
                }
            }
            const float g0 = (s0a+s0b)+(s0c+s0d);
            const float g1 = (s1a+s1b)+(s1c+s1d);
            float xn0, xn1;
            if (first) { xn0 = g0; xn1 = g1; }
            else {
                const unsigned old = dst[v];      // own row's x_{k-2}; owner-only RMW
                xn0 = fmaf(2.f, g0, -__half2float(__ushort_as_half((unsigned short)(old & 0xFFFFu))));
                xn1 = fmaf(2.f, g1, -__half2float(__ushort_as_half((unsigned short)(old >> 16))));
            }
            if (!last) {
                __half2 hh = __floats2half2_rn(xn0, xn1);
                dst[v] = *(const unsigned*)&hh;
            }
            const unsigned h0 = f2bf(xn0), h1 = f2bf(xn1);
            if (plane < 0) { tlo0[r] = h0; tlo1[r] = h1; }
            else {
                p0[(size_t)plane*V + v] = tlo0[r] | (h0 << 16);
                p1[(size_t)plane*V + v] = tlo1[r] | (h1 << 16);
            }
        }
        __syncthreads();
    };

    step(buf, buf + V, true, false, 0);                 // k=1, flush pair 0
    for (int k = 2; k < 24; k += 2) {
        step(buf + V, buf, false, false, -1);           // even k: stash
        step(buf, buf + V, false, false, (k + 1) >> 1); // odd k: flush pair
    }
    step(buf + V, buf, false, true, -1);                // k=24: stash only

#pragma unroll
    for (int r = 0; r < RPT; ++r) {                     // pair 12 = {bf16(x24), 0}
        const int v = r*THREADS + t;
        p0[(size_t)12*V + v] = tlo0[r];
        p1[(size_t)12*V + v] = tlo1[r];
    }
}

// ---------- W prep: Wb[fin][g][f][kk] = bf16(W[f][fin*25 + g*8+kk]), 0-padded ----------
template<int FIN, int F>
__global__ __launch_bounds__(256) void k_wprep(const float* __restrict__ W,
                                               unsigned short* __restrict__ Wb) {
    int idx = blockIdx.x*256 + threadIdx.x;
    int kk  = idx & 7;
    int f   = (idx >> 3) % F;
    int g   = (idx >> 3) / F % 4;
    int fin = idx / (8*F*4);
    int k = g*8 + kk;
    Wb[idx] = (k < K_) ? f2bf(W[(size_t)f*(FIN*K_) + fin*K_ + k]) : 0;
}

// ---------- layer-1 MFMA GEMM + relu + pool -> X0T2[(f*64+b)][v2] ----------
__global__ __launch_bounds__(256) void k_gemm1(const unsigned* __restrict__ STK,
                                               const unsigned short* __restrict__ Wb,
                                               const float* __restrict__ bias,
                                               float* __restrict__ X0T2) {
    __shared__ float Tsm[32][36];
    const int t = threadIdx.x, lane = t & 63, wave = t >> 6;
    const int b = blockIdx.x;
    const int v0 = blockIdx.y*128 + wave*32;
    const int m = lane & 15, g = lane >> 4;
    int offp[4];
#pragma unroll
    for (int p = 0; p < 4; ++p) {
        int pl = 4*g + p; if (pl > 12) pl = 12;   // clamp: k>=26 lands on pair12, Wb=0 kills it
        offp[p] = pl*V1_ + v0 + m;
    }

    f32x4 acc[2][2];
#pragma unroll
    for (int mt = 0; mt < 2; ++mt)
#pragma unroll
        for (int ft = 0; ft < 2; ++ft) acc[mt][ft] = (f32x4){0.f,0.f,0.f,0.f};

#pragma unroll
    for (int fin = 0; fin < DF_; ++fin) {
        const unsigned* sp = STK + (size_t)(fin*64 + b)*(NP_*V1_);
        unsigned ua[4], ub[4];
#pragma unroll
        for (int p = 0; p < 4; ++p) { ua[p] = sp[offp[p]]; ub[p] = sp[offp[p] + 16]; }
        bf16x8 a0, a1;
        __builtin_memcpy(&a0, ua, 16);
        __builtin_memcpy(&a1, ub, 16);
        const bf16x8 w0 = *(const bf16x8*)&Wb[((fin*4+g)*F1_ + m)*8];
        const bf16x8 w1 = *(const bf16x8*)&Wb[((fin*4+g)*F1_ + 16 + m)*8];
        acc[0][0] = __builtin_amdgcn_mfma_f32_16x16x32_bf16(a0, w0, acc[0][0], 0,0,0);
        acc[0][1] = __builtin_amdgcn_mfma_f32_16x16x32_bf16(a0, w1, acc[0][1], 0,0,0);
        acc[1][0] = __builtin_amdgcn_mfma_f32_16x16x32_bf16(a1, w0, acc[1][0], 0,0,0);
        acc[1][1] = __builtin_amdgcn_mfma_f32_16x16x32_bf16(a1, w1, acc[1][1], 0,0,0);
    }
    float bv[2] = { bias[m], bias[16+m] };
#pragma unroll
    for (int mt = 0; mt < 2; ++mt)
#pragma unroll
        for (int ft = 0; ft < 2; ++ft) {
            f32x4 a = acc[mt][ft];
            float mx = fmaxf(fmaxf(a[0],a[1]), fmaxf(a[2],a[3])) + bv[ft];
            Tsm[ft*16 + m][wave*8 + mt*4 + g] = fmaxf(mx, 0.f);
        }
    __syncthreads();
    const int f = t >> 3, vg = t & 7;
    float4 o = *(const float4*)&Tsm[f][vg*4];
    *(float4*)&X0T2[(size_t)(f*64+b)*V2_ + blockIdx.y*32 + vg*4] = o;
}

// ---------- layer-2 MFMA GEMM + relu + pool -> FCINT[v2*64+f][b] ----------
__global__ __launch_bounds__(256) void k_gemm2(const unsigned* __restrict__ STK,
                                               const unsigned short* __restrict__ Wb,
                                               const float* __restrict__ bias,
                                               float* __restrict__ FCINT) {
    const int t = threadIdx.x, lane = t & 63, wave = t >> 6;
    const int b = blockIdx.x;
    const int v0 = blockIdx.y*128 + wave*32;
    const int m = lane & 15, g = lane >> 4;
    int offp[4];
#pragma unroll
    for (int p = 0; p < 4; ++p) {
        int pl = 4*g + p; if (pl > 12) pl = 12;
        offp[p] = pl*V2_ + v0 + m;
    }

    f32x4 acc[2][4];
#pragma unroll
    for (int mt = 0; mt < 2; ++mt)
#pragma unroll
        for (int ft = 0; ft < 4; ++ft) acc[mt][ft] = (f32x4){0.f,0.f,0.f,0.f};

#pragma unroll 4
    for (int fin = 0; fin < F1_; ++fin) {
        const unsigned* sp = STK + (size_t)(fin*64 + b)*(NP_*V2_);
        unsigned ua[4], ub[4];
#pragma unroll
        for (int p = 0; p < 4; ++p) { ua[p] = sp[offp[p]]; ub[p] = sp[offp[p] + 16]; }
        bf16x8 a0, a1;
        __builtin_memcpy(&a0, ua, 16);
        __builtin_memcpy(&a1, ub, 16);
#pragma unroll
        for (int ft = 0; ft < 4; ++ft) {
            const bf16x8 bw = *(const bf16x8*)&Wb[((fin*4+g)*F2_ + ft*16 + m)*8];
            acc[0][ft] = __builtin_amdgcn_mfma_f32_16x16x32_bf16(a0, bw, acc[0][ft], 0,0,0);
            acc[1][ft] = __builtin_amdgcn_mfma_f32_16x16x32_bf16(a1, bw, acc[1][ft], 0,0,0);
        }
    }
#pragma unroll
    for (int mt = 0; mt < 2; ++mt)
#pragma unroll
        for (int ft = 0; ft < 4; ++ft) {
            f32x4 a = acc[mt][ft];
            float mx = fmaxf(fmaxf(a[0],a[1]), fmaxf(a[2],a[3])) + bias[ft*16 + m];
            mx = fmaxf(mx, 0.f);
            int v2 = blockIdx.y*32 + wave*8 + mt*4 + g;
            FCINT[((size_t)v2*64 + ft*16 + m)*64 + b] = mx;
        }
}

// ---------- FC1: O[b][j] (+= atomics over i-splits), AT layout [i][b] ----------
__global__ __launch_bounds__(256) void k_fc1_init(const float* __restrict__ bias,
                                                  float* __restrict__ O) {
    int idx = blockIdx.x*256 + threadIdx.x;
    O[idx] = bias[idx & (FC1F_-1)];
}

__global__ __launch_bounds__(256) void k_fc1(const float* __restrict__ AT,
                                             const float* __restrict__ W,
                                             float* __restrict__ O) {
    const int t = threadIdx.x;
    const int b = t & 63;
    const int jq = __builtin_amdgcn_readfirstlane(t >> 6);
    const int j0 = blockIdx.x*32 + jq*8;
    const int i0 = blockIdx.y*1024;
    float acc[8] = {};
    for (int i = i0; i < i0 + 1024; i += 4) {
        float a0 = AT[(size_t)(i+0)*64 + b];
        float a1 = AT[(size_t)(i+1)*64 + b];
        float a2 = AT[(size_t)(i+2)*64 + b];
        float a3 = AT[(size_t)(i+3)*64 + b];
#pragma unroll
        for (int jj = 0; jj < 8; ++jj) {
            const float* wp = &W[(size_t)(j0+jj)*FCIN_ + i];
            acc[jj] = fmaf(a0, wp[0], acc[jj]);
            acc[jj] = fmaf(a1, wp[1], acc[jj]);
            acc[jj] = fmaf(a2, wp[2], acc[jj]);
            acc[jj] = fmaf(a3, wp[3], acc[jj]);
        }
    }
#pragma unroll
    for (int jj = 0; jj < 8; ++jj)
        atomicAdd(&O[b*FC1F_ + j0 + jj], acc[jj]);
}

// ---------- FC2 (relu on FC1 output applied here) ----------
__global__ void k_fc2(const float* __restrict__ O1, const float* __restrict__ W2,
                      const float* __restrict__ b2, float* __restrict__ out) {
    int c = blockIdx.x;
    int b = threadIdx.x;
    float s = b2[c];
    for (int j = 0; j < FC1F_; ++j)
        s = fmaf(fmaxf(O1[b*FC1F_ + j], 0.f), W2[c*FC1F_ + j], s);
    out[b*FC2F_ + c] = s;
}

extern "C" void kernel_launch(void* const* d_in, const int* in_sizes, int n_in,
                              void* d_out, int out_size, void* d_ws, size_t ws_size,
                              hipStream_t stream) {
    const float* x   = (const float*)d_in[0];
    const int*   l1r = (const int*)d_in[1];
    const int*   l1c = (const int*)d_in[2];
    const float* l1v = (const float*)d_in[3];
    const int*   l2r = (const int*)d_in[4];
    const int*   l2c = (const int*)d_in[5];
    const float* l2v = (const float*)d_in[6];
    const float* w1  = (const float*)d_in[7];
    const float* b1  = (const float*)d_in[8];
    const float* w2  = (const float*)d_in[9];
    const float* b2  = (const float*)d_in[10];
    const float* fw1 = (const float*)d_in[11];
    const float* fb1 = (const float*)d_in[12];
    const float* fw2 = (const float*)d_in[13];
    const float* fb2 = (const float*)d_in[14];
    float* out = (float*)d_out;

    char* wsp = (char*)d_ws;
    size_t off = 0;
    auto alloc = [&](size_t bytes) -> void* {
        void* p = wsp + off;
        off += (bytes + 255) & ~size_t(255);
        return p;
    };
    float*    X0T1  = (float*)alloc((size_t)C1_*V1_*4);
    unsigned* STACK = (unsigned*)alloc((size_t)C1_*NP_*V1_*4);   // == C2_*NP_*V2_*4, reused
    float*    X0T2  = (float*)alloc((size_t)C2_*V2_*4);
    float*    FCINT = (float*)alloc((size_t)FCIN_*B_*4);
    float*    FC1O  = (float*)alloc((size_t)B_*FC1F_*4);
    unsigned short* WB1 = (unsigned short*)alloc((size_t)DF_*4*F1_*8*2);
    unsigned short* WB2 = (unsigned short*)alloc((size_t)F1_*4*F2_*8*2);
    int*      cnt1  = (int*)alloc(V1_*4);
    int*      offs1 = (int*)alloc((V1_+1)*4);
    int*      cur1  = (int*)alloc(V1_*4);
    unsigned* ep1   = (unsigned*)alloc((size_t)(E1_ + 4*V1_)*4);
    int*      cnt2  = (int*)alloc(V2_*4);
    int*      offs2 = (int*)alloc((V2_+1)*4);
    int*      cur2  = (int*)alloc(V2_*4);
    unsigned* ep2   = (unsigned*)alloc((size_t)(E2_ + 4*V2_)*4);

    // --- CSR build both layers + W prep ---
    hipMemsetAsync(cnt1, 0, V1_*4, stream);
    hipMemsetAsync(ep1, 0, (size_t)(E1_ + 4*V1_)*4, stream);
    hipMemsetAsync(cnt2, 0, V2_*4, stream);
    hipMemsetAsync(ep2, 0, (size_t)(E2_ + 4*V2_)*4, stream);
    hipLaunchKernelGGL(k_count,   dim3(E1_/256), dim3(256), 0, stream, l1r, E1_, cnt1);
    hipLaunchKernelGGL(k_scan,    dim3(1),       dim3(256), 0, stream, cnt1, V1_, offs1, cur1);
    hipLaunchKernelGGL(k_scatter, dim3(E1_/256), dim3(256), 0, stream, l1r, l1c, l1v, E1_, cur1, ep1);
    hipLaunchKernelGGL(k_count,   dim3(E2_/256), dim3(256), 0, stream, l2r, E2_, cnt2);
    hipLaunchKernelGGL(k_scan,    dim3(1),       dim3(256), 0, stream, cnt2, V2_, offs2, cur2);
    hipLaunchKernelGGL(k_scatter, dim3(E2_/256), dim3(256), 0, stream, l2r, l2c, l2v, E2_, cur2, ep2);
    hipLaunchKernelGGL((k_wprep<DF_,F1_>), dim3(DF_*4*F1_*8/256), dim3(256), 0, stream, w1, WB1);
    hipLaunchKernelGGL((k_wprep<F1_,F2_>), dim3(F1_*4*F2_*8/256), dim3(256), 0, stream, w2, WB2);

    // --- layer 1 ---
    hipLaunchKernelGGL(k_transpose_x, dim3(V1_/16), dim3(256), 0, stream, x, X0T1);
    hipLaunchKernelGGL((k_cheb<V1_,1024,8>), dim3(C1_/2), dim3(1024), 0, stream,
                       X0T1, offs1, ep1, STACK);
    hipLaunchKernelGGL(k_gemm1, dim3(64, 32), dim3(256), 0, stream, STACK, WB1, b1, X0T2);

    // --- layer 2 ---
    hipLaunchKernelGGL((k_cheb<V2_,512,8>), dim3(C2_/2), dim3(512), 0, stream,
                       X0T2, offs2, ep2, STACK);
    hipLaunchKernelGGL(k_gemm2, dim3(64, 8), dim3(256), 0, stream, STACK, WB2, b2, FCINT);

    // --- FC ---
    hipLaunchKernelGGL(k_fc1_init, dim3(B_*FC1F_/256), dim3(256), 0, stream, fb1, FC1O);
    hipLaunchKernelGGL(k_fc1, dim3(16, 16), dim3(256), 0, stream, FCINT, fw1, FC1O);
    hipLaunchKernelGGL(k_fc2, dim3(FC2F_), dim3(B_), 0, stream, FC1O, fw2, fb2, out);
}

// Round 6
// 728.557 us; speedup vs baseline: 1.4360x; 1.0023x over previous
//
#include <hip/hip_runtime.h>
#include <hip/hip_fp16.h>

#define B_    64
#define V1_   4096
#define V2_   1024
#define DF_   8
#define K_    25
#define NP_   13      /* u32 pair-planes per column: pairs (k0,k1)..(k24,-) */
#define F1_   32
#define F2_   64
#define FC1F_ 512
#define FC2F_ 10
#define E1_   65536
#define E2_   16384
#define C1_   512
#define C2_   2048
#define FCIN_ 16384

typedef short bf16x8 __attribute__((ext_vector_type(8)));
typedef float f32x4  __attribute__((ext_vector_type(4)));

__device__ __forceinline__ unsigned short f2bf(float x) {
    unsigned u = __float_as_uint(x);
    u += 0x7FFFu + ((u >> 16) & 1u);
    return (unsigned short)(u >> 16);
}

// ---------- input transpose: x[b,v,fin] -> X0T[(fin*64+b)][v] ----------
__global__ __launch_bounds__(256) void k_transpose_x(const float* __restrict__ x,
                                                     float* __restrict__ X0T) {
    __shared__ float tsh[DF_][B_][16];
    const int t = threadIdx.x;
    const int v0 = blockIdx.x * 16;
    for (int rep = 0; rep < 4; ++rep) {
        int idx = rep*256 + t;
        int b = idx >> 4, vv = idx & 15;
        const float4* p = (const float4*)&x[((size_t)b*V1_ + v0 + vv)*DF_];
        float4 a0 = p[0], a1 = p[1];
        tsh[0][b][vv]=a0.x; tsh[1][b][vv]=a0.y; tsh[2][b][vv]=a0.z; tsh[3][b][vv]=a0.w;
        tsh[4][b][vv]=a1.x; tsh[5][b][vv]=a1.y; tsh[6][b][vv]=a1.z; tsh[7][b][vv]=a1.w;
    }
    __syncthreads();
    for (int rep = 0; rep < 32; ++rep) {
        int idx = rep*256 + t;
        int vv = idx & 15, b = (idx >> 4) & 63, fin = idx >> 10;
        X0T[(size_t)(fin*64 + b)*V1_ + v0 + vv] = tsh[fin][b][vv];
    }
}

// ---------- CSR build (padded to 4-edge alignment, packed 4B edges) ----------
__global__ __launch_bounds__(256) void k_count(const int* __restrict__ rows, int E,
                                               int* __restrict__ cnt) {
    int e = blockIdx.x*256 + threadIdx.x;
    if (e < E) atomicAdd(&cnt[rows[e]], 1);
}

__global__ __launch_bounds__(256) void k_scan(const int* __restrict__ cnt, int V,
                                              int* __restrict__ offs, int* __restrict__ cursor) {
    __shared__ int psum[256];
    int t = threadIdx.x;
    int chunk = V >> 8;
    int lo = t*chunk;
    int s = 0;
    for (int i = lo; i < lo+chunk; ++i) s += (cnt[i] + 3) & ~3;
    psum[t] = s;
    __syncthreads();
    for (int off = 1; off < 256; off <<= 1) {
        int val = (t >= off) ? psum[t-off] : 0;
        __syncthreads();
        psum[t] += val;
        __syncthreads();
    }
    int run = (t == 0) ? 0 : psum[t-1];
    for (int i = lo; i < lo+chunk; ++i) {
        offs[i] = run; cursor[i] = run;
        run += (cnt[i] + 3) & ~3;
    }
    if (t == 255) offs[V] = run;
}

// edge payload: {f16 weight hi16, (col*4) lo16} -> col*4 = byte offset into f16x2 state
__global__ __launch_bounds__(256) void k_scatter(const int* __restrict__ rows,
                                                 const int* __restrict__ cols,
                                                 const float* __restrict__ vals, int E,
                                                 int* __restrict__ cursor,
                                                 unsigned* __restrict__ ep) {
    int e = blockIdx.x*256 + threadIdx.x;
    if (e < E) {
        int p = atomicAdd(&cursor[rows[e]], 1);
        unsigned hv = (unsigned)__half_as_ushort(__float2half(vals[e]));
        ep[p] = (hv << 16) | ((unsigned)cols[e] << 2);
    }
}

// ---------- persistent Chebyshev recursion: 2 cols/block, f16x2 LDS ping-pong ----------
// stack: u32 pair-planes  stk[(c*13 + pair)*V + v] = bf16(x_{2p}) | bf16(x_{2p+1})<<16
template<int V, int THREADS, int MINW>
__global__ __launch_bounds__(THREADS, MINW) void k_cheb(
        const float* __restrict__ X0T,
        const int* __restrict__ offs,
        const unsigned* __restrict__ ep,
        unsigned* __restrict__ stk) {
    constexpr int RPT = V / THREADS;
    __shared__ unsigned buf[2*V];
    const int c0 = blockIdx.x*2;
    const int t = threadIdx.x;
    int e0r[RPT], e1r[RPT];
    unsigned tlo0[RPT], tlo1[RPT];
    unsigned* __restrict__ p0 = stk + (size_t)(c0+0)*NP_*V;
    unsigned* __restrict__ p1 = stk + (size_t)(c0+1)*NP_*V;

    // k = 0
#pragma unroll
    for (int r = 0; r < RPT; ++r) {
        const int v = r*THREADS + t;
        e0r[r] = offs[v]; e1r[r] = offs[v+1];
        const float x0 = X0T[(size_t)c0*V + v];
        const float x1 = X0T[(size_t)(c0+1)*V + v];
        __half2 hh = __floats2half2_rn(x0, x1);
        buf[v] = *(const unsigned*)&hh;
        tlo0[r] = f2bf(x0); tlo1[r] = f2bf(x1);
    }
    __syncthreads();

    // one Chebyshev step: gather src, write dst; plane>=0 -> flush pair, else stash tlo
    auto step = [&](const unsigned* __restrict__ src, unsigned* __restrict__ dst,
                    bool first, bool last, int plane) {
#pragma unroll
        for (int r = 0; r < RPT; ++r) {
            const int v = r*THREADS + t;
            float s0a=0.f,s0b=0.f,s0c=0.f,s0d=0.f;
            float s1a=0.f,s1b=0.f,s1c=0.f,s1d=0.f;
            const int e1 = e1r[r];
            for (int e = e0r[r]; e < e1; e += 4) {
                const uint4 q = *(const uint4*)&ep[e];
                {
                    const float wf = __half2float(__ushort_as_half((unsigned short)(q.x>>16)));
                    const unsigned g = *(const unsigned*)((const char*)src + (q.x & 0xFFFFu));
                    s0a = fmaf(wf, __half2float(__ushort_as_half((unsigned short)(g & 0xFFFFu))), s0a);
                    s1a = fmaf(wf, __half2float(__ushort_as_half((unsigned short)(g >> 16))), s1a);
                }
                {
                    const float wf = __half2float(__ushort_as_half((unsigned short)(q.y>>16)));
                    const unsigned g = *(const unsigned*)((const char*)src + (q.y & 0xFFFFu));
                    s0b = fmaf(wf, __half2float(__ushort_as_half((unsigned short)(g & 0xFFFFu))), s0b);
                    s1b = fmaf(wf, __half2float(__ushort_as_half((unsigned short)(g >> 16))), s1b);
                }
                {
                    const float wf = __half2float(__ushort_as_half((unsigned short)(q.z>>16)));
                    const unsigned g = *(const unsigned*)((const char*)src + (q.z & 0xFFFFu));
                    s0c = fmaf(wf, __half2float(__ushort_as_half((unsigned short)(g & 0xFFFFu))), s0c);
                    s1c = fmaf(wf, __half2float(__ushort_as_half((unsigned short)(g >> 16))), s1c);
                }
                {
                    const float wf = __half2float(__ushort_as_half((unsigned short)(q.w>>16)));
                    const unsigned g = *(const unsigned*)((const char*)src + (q.w & 0xFFFFu));
                    s0d = fmaf(wf, __half2float(__ushort_as_half((unsigned short)(g & 0xFFFFu))), s0d);
                    s1d = fmaf(wf, __half2float(__ushort_as_half((unsigned short)(g >> 16))), s1d);
                }
            }
            const float g0 = (s0a+s0b)+(s0c+s0d);
            const float g1 = (s1a+s1b)+(s1c+s1d);
            float xn0, xn1;
            if (first) { xn0 = g0; xn1 = g1; }
            else {
                const unsigned old = dst[v];      // own row's x_{k-2}; owner-only RMW
                xn0 = fmaf(2.f, g0, -__half2float(__ushort_as_half((unsigned short)(old & 0xFFFFu))));
                xn1 = fmaf(2.f, g1, -__half2float(__ushort_as_half((unsigned short)(old >> 16))));
            }
            if (!last) {
                __half2 hh = __floats2half2_rn(xn0, xn1);
                dst[v] = *(const unsigned*)&hh;
            }
            const unsigned h0 = f2bf(xn0), h1 = f2bf(xn1);
            if (plane < 0) { tlo0[r] = h0; tlo1[r] = h1; }
            else {
                p0[(size_t)plane*V + v] = tlo0[r] | (h0 << 16);
                p1[(size_t)plane*V + v] = tlo1[r] | (h1 << 16);
            }
        }
        __syncthreads();
    };

    step(buf, buf + V, true, false, 0);                 // k=1, flush pair 0
    for (int k = 2; k < 24; k += 2) {
        step(buf + V, buf, false, false, -1);           // even k: stash
        step(buf, buf + V, false, false, (k + 1) >> 1); // odd k: flush pair
    }
    step(buf + V, buf, false, true, -1);                // k=24: stash only

#pragma unroll
    for (int r = 0; r < RPT; ++r) {                     // pair 12 = {bf16(x24), 0}
        const int v = r*THREADS + t;
        p0[(size_t)12*V + v] = tlo0[r];
        p1[(size_t)12*V + v] = tlo1[r];
    }
}

// ---------- W prep: Wb[fin][g][f][kk] = bf16(W[f][fin*25 + g*8+kk]), 0-padded ----------
template<int FIN, int F>
__global__ __launch_bounds__(256) void k_wprep(const float* __restrict__ W,
                                               unsigned short* __restrict__ Wb) {
    int idx = blockIdx.x*256 + threadIdx.x;
    int kk  = idx & 7;
    int f   = (idx >> 3) % F;
    int g   = (idx >> 3) / F % 4;
    int fin = idx / (8*F*4);
    int k = g*8 + kk;
    Wb[idx] = (k < K_) ? f2bf(W[(size_t)f*(FIN*K_) + fin*K_ + k]) : 0;
}

// ---------- layer-1 MFMA GEMM + relu + pool -> X0T2[(f*64+b)][v2] ----------
__global__ __launch_bounds__(256) void k_gemm1(const unsigned* __restrict__ STK,
                                               const unsigned short* __restrict__ Wb,
                                               const float* __restrict__ bias,
                                               float* __restrict__ X0T2) {
    __shared__ float Tsm[32][36];
    const int t = threadIdx.x, lane = t & 63, wave = t >> 6;
    const int b = blockIdx.x;
    const int v0 = blockIdx.y*128 + wave*32;
    const int m = lane & 15, g = lane >> 4;
    int offp[4];
#pragma unroll
    for (int p = 0; p < 4; ++p) {
        int pl = 4*g + p; if (pl > 12) pl = 12;   // clamp: k>=26 lands on pair12, Wb=0 kills it
        offp[p] = pl*V1_ + v0 + m;
    }

    f32x4 acc[2][2];
#pragma unroll
    for (int mt = 0; mt < 2; ++mt)
#pragma unroll
        for (int ft = 0; ft < 2; ++ft) acc[mt][ft] = (f32x4){0.f,0.f,0.f,0.f};

#pragma unroll
    for (int fin = 0; fin < DF_; ++fin) {
        const unsigned* sp = STK + (size_t)(fin*64 + b)*(NP_*V1_);
        unsigned ua[4], ub[4];
#pragma unroll
        for (int p = 0; p < 4; ++p) { ua[p] = sp[offp[p]]; ub[p] = sp[offp[p] + 16]; }
        bf16x8 a0, a1;
        __builtin_memcpy(&a0, ua, 16);
        __builtin_memcpy(&a1, ub, 16);
        const bf16x8 w0 = *(const bf16x8*)&Wb[((fin*4+g)*F1_ + m)*8];
        const bf16x8 w1 = *(const bf16x8*)&Wb[((fin*4+g)*F1_ + 16 + m)*8];
        acc[0][0] = __builtin_amdgcn_mfma_f32_16x16x32_bf16(a0, w0, acc[0][0], 0,0,0);
        acc[0][1] = __builtin_amdgcn_mfma_f32_16x16x32_bf16(a0, w1, acc[0][1], 0,0,0);
        acc[1][0] = __builtin_amdgcn_mfma_f32_16x16x32_bf16(a1, w0, acc[1][0], 0,0,0);
        acc[1][1] = __builtin_amdgcn_mfma_f32_16x16x32_bf16(a1, w1, acc[1][1], 0,0,0);
    }
    float bv[2] = { bias[m], bias[16+m] };
#pragma unroll
    for (int mt = 0; mt < 2; ++mt)
#pragma unroll
        for (int ft = 0; ft < 2; ++ft) {
            f32x4 a = acc[mt][ft];
            float mx = fmaxf(fmaxf(a[0],a[1]), fmaxf(a[2],a[3])) + bv[ft];
            Tsm[ft*16 + m][wave*8 + mt*4 + g] = fmaxf(mx, 0.f);
        }
    __syncthreads();
    const int f = t >> 3, vg = t & 7;
    float4 o = *(const float4*)&Tsm[f][vg*4];
    *(float4*)&X0T2[(size_t)(f*64+b)*V2_ + blockIdx.y*32 + vg*4] = o;
}

// ---------- layer-2 MFMA GEMM + relu + pool -> FCINT[v2*64+f][b] ----------
__global__ __launch_bounds__(256) void k_gemm2(const unsigned* __restrict__ STK,
                                               const unsigned short* __restrict__ Wb,
                                               const float* __restrict__ bias,
                                               float* __restrict__ FCINT) {
    const int t = threadIdx.x, lane = t & 63, wave = t >> 6;
    const int b = blockIdx.x;
    const int v0 = blockIdx.y*128 + wave*32;
    const int m = lane & 15, g = lane >> 4;
    int offp[4];
#pragma unroll
    for (int p = 0; p < 4; ++p) {
        int pl = 4*g + p; if (pl > 12) pl = 12;
        offp[p] = pl*V2_ + v0 + m;
    }

    f32x4 acc[2][4];
#pragma unroll
    for (int mt = 0; mt < 2; ++mt)
#pragma unroll
        for (int ft = 0; ft < 4; ++ft) acc[mt][ft] = (f32x4){0.f,0.f,0.f,0.f};

#pragma unroll 4
    for (int fin = 0; fin < F1_; ++fin) {
        const unsigned* sp = STK + (size_t)(fin*64 + b)*(NP_*V2_);
        unsigned ua[4], ub[4];
#pragma unroll
        for (int p = 0; p < 4; ++p) { ua[p] = sp[offp[p]]; ub[p] = sp[offp[p] + 16]; }
        bf16x8 a0, a1;
        __builtin_memcpy(&a0, ua, 16);
        __builtin_memcpy(&a1, ub, 16);
#pragma unroll
        for (int ft = 0; ft < 4; ++ft) {
            const bf16x8 bw = *(const bf16x8*)&Wb[((fin*4+g)*F2_ + ft*16 + m)*8];
            acc[0][ft] = __builtin_amdgcn_mfma_f32_16x16x32_bf16(a0, bw, acc[0][ft], 0,0,0);
            acc[1][ft] = __builtin_amdgcn_mfma_f32_16x16x32_bf16(a1, bw, acc[1][ft], 0,0,0);
        }
    }
#pragma unroll
    for (int mt = 0; mt < 2; ++mt)
#pragma unroll
        for (int ft = 0; ft < 4; ++ft) {
            f32x4 a = acc[mt][ft];
            float mx = fmaxf(fmaxf(a[0],a[1]), fmaxf(a[2],a[3])) + bias[ft*16 + m];
            mx = fmaxf(mx, 0.f);
            int v2 = blockIdx.y*32 + wave*8 + mt*4 + g;
            FCINT[((size_t)v2*64 + ft*16 + m)*64 + b] = mx;
        }
}

// ---------- FC1: O[b][j] (+= atomics over i-splits), AT layout [i][b] ----------
__global__ __launch_bounds__(256) void k_fc1_init(const float* __restrict__ bias,
                                                  float* __restrict__ O) {
    int idx = blockIdx.x*256 + threadIdx.x;
    O[idx] = bias[idx & (FC1F_-1)];
}

__global__ __launch_bounds__(256) void k_fc1(const float* __restrict__ AT,
                                             const float* __restrict__ W,
                                             float* __restrict__ O) {
    const int t = threadIdx.x;
    const int b = t & 63;
    const int jq = __builtin_amdgcn_readfirstlane(t >> 6);
    const int j0 = blockIdx.x*32 + jq*8;
    const int i0 = blockIdx.y*1024;
    float acc[8] = {};
    for (int i = i0; i < i0 + 1024; i += 4) {
        float a0 = AT[(size_t)(i+0)*64 + b];
        float a1 = AT[(size_t)(i+1)*64 + b];
        float a2 = AT[(size_t)(i+2)*64 + b];
        float a3 = AT[(size_t)(i+3)*64 + b];
#pragma unroll
        for (int jj = 0; jj < 8; ++jj) {
            const float* wp = &W[(size_t)(j0+jj)*FCIN_ + i];
            acc[jj] = fmaf(a0, wp[0], acc[jj]);
            acc[jj] = fmaf(a1, wp[1], acc[jj]);
            acc[jj] = fmaf(a2, wp[2], acc[jj]);
            acc[jj] = fmaf(a3, wp[3], acc[jj]);
        }
    }
#pragma unroll
    for (int jj = 0; jj < 8; ++jj)
        atomicAdd(&O[b*FC1F_ + j0 + jj], acc[jj]);
}

// ---------- FC2 (relu on FC1 output applied here) ----------
__global__ void k_fc2(const float* __restrict__ O1, const float* __restrict__ W2,
                      const float* __restrict__ b2, float* __restrict__ out) {
    int c = blockIdx.x;
    int b = threadIdx.x;
    float s = b2[c];
    for (int j = 0; j < FC1F_; ++j)
        s = fmaf(fmaxf(O1[b*FC1F_ + j], 0.f), W2[c*FC1F_ + j], s);
    out[b*FC2F_ + c] = s;
}

extern "C" void kernel_launch(void* const* d_in, const int* in_sizes, int n_in,
                              void* d_out, int out_size, void* d_ws, size_t ws_size,
                              hipStream_t stream) {
    const float* x   = (const float*)d_in[0];
    const int*   l1r = (const int*)d_in[1];
    const int*   l1c = (const int*)d_in[2];
    const float* l1v = (const float*)d_in[3];
    const int*   l2r = (const int*)d_in[4];
    const int*   l2c = (const int*)d_in[5];
    const float* l2v = (const float*)d_in[6];
    const float* w1  = (const float*)d_in[7];
    const float* b1  = (const float*)d_in[8];
    const float* w2  = (const float*)d_in[9];
    const float* b2  = (const float*)d_in[10];
    const float* fw1 = (const float*)d_in[11];
    const float* fb1 = (const float*)d_in[12];
    const float* fw2 = (const float*)d_in[13];
    const float* fb2 = (const float*)d_in[14];
    float* out = (float*)d_out;

    char* wsp = (char*)d_ws;
    size_t off = 0;
    auto alloc = [&](size_t bytes) -> void* {
        void* p = wsp + off;
        off += (bytes + 255) & ~size_t(255);
        return p;
    };
    float*    X0T1  = (float*)alloc((size_t)C1_*V1_*4);
    unsigned* STACK = (unsigned*)alloc((size_t)C1_*NP_*V1_*4);   // == C2_*NP_*V2_*4, reused
    float*    X0T2  = (float*)alloc((size_t)C2_*V2_*4);
    float*    FCINT = (float*)alloc((size_t)FCIN_*B_*4);
    float*    FC1O  = (float*)alloc((size_t)B_*FC1F_*4);
    unsigned short* WB1 = (unsigned short*)alloc((size_t)DF_*4*F1_*8*2);
    unsigned short* WB2 = (unsigned short*)alloc((size_t)F1_*4*F2_*8*2);
    int*      cnt1  = (int*)alloc(V1_*4);
    int*      offs1 = (int*)alloc((V1_+1)*4);
    int*      cur1  = (int*)alloc(V1_*4);
    unsigned* ep1   = (unsigned*)alloc((size_t)(E1_ + 4*V1_)*4);
    int*      cnt2  = (int*)alloc(V2_*4);
    int*      offs2 = (int*)alloc((V2_+1)*4);
    int*      cur2  = (int*)alloc(V2_*4);
    unsigned* ep2   = (unsigned*)alloc((size_t)(E2_ + 4*V2_)*4);

    // --- CSR build both layers + W prep ---
    hipMemsetAsync(cnt1, 0, V1_*4, stream);
    hipMemsetAsync(ep1, 0, (size_t)(E1_ + 4*V1_)*4, stream);
    hipMemsetAsync(cnt2, 0, V2_*4, stream);
    hipMemsetAsync(ep2, 0, (size_t)(E2_ + 4*V2_)*4, stream);
    hipLaunchKernelGGL(k_count,   dim3(E1_/256), dim3(256), 0, stream, l1r, E1_, cnt1);
    hipLaunchKernelGGL(k_scan,    dim3(1),       dim3(256), 0, stream, cnt1, V1_, offs1, cur1);
    hipLaunchKernelGGL(k_scatter, dim3(E1_/256), dim3(256), 0, stream, l1r, l1c, l1v, E1_, cur1, ep1);
    hipLaunchKernelGGL(k_count,   dim3(E2_/256), dim3(256), 0, stream, l2r, E2_, cnt2);
    hipLaunchKernelGGL(k_scan,    dim3(1),       dim3(256), 0, stream, cnt2, V2_, offs2, cur2);
    hipLaunchKernelGGL(k_scatter, dim3(E2_/256), dim3(256), 0, stream, l2r, l2c, l2v, E2_, cur2, ep2);
    hipLaunchKernelGGL((k_wprep<DF_,F1_>), dim3(DF_*4*F1_*8/256), dim3(256), 0, stream, w1, WB1);
    hipLaunchKernelGGL((k_wprep<F1_,F2_>), dim3(F1_*4*F2_*8/256), dim3(256), 0, stream, w2, WB2);

    // --- layer 1 ---
    hipLaunchKernelGGL(k_transpose_x, dim3(V1_/16), dim3(256), 0, stream, x, X0T1);
    hipLaunchKernelGGL((k_cheb<V1_,1024,8>), dim3(C1_/2), dim3(1024), 0, stream,
                       X0T1, offs1, ep1, STACK);
    hipLaunchKernelGGL(k_gemm1, dim3(64, 32), dim3(256), 0, stream, STACK, WB1, b1, X0T2);

    // --- layer 2 ---
    hipLaunchKernelGGL((k_cheb<V2_,512,8>), dim3(C2_/2), dim3(512), 0, stream,
                       X0T2, offs2, ep2, STACK);
    hipLaunchKernelGGL(k_gemm2, dim3(64, 8), dim3(256), 0, stream, STACK, WB2, b2, FCINT);

    // --- FC ---
    hipLaunchKernelGGL(k_fc1_init, dim3(B_*FC1F_/256), dim3(256), 0, stream, fb1, FC1O);
    hipLaunchKernelGGL(k_fc1, dim3(16, 16), dim3(256), 0, stream, FCINT, fw1, FC1O);
    hipLaunchKernelGGL(k_fc2, dim3(FC2F_), dim3(B_), 0, stream, FC1O, fw2, fb2, out);
}